// Round 4
// baseline (96.763 us; speedup 1.0000x reference)
//
#include <hip/hip_runtime.h>

#define BATCH    16
#define BASE_N   64
#define VNUM     100000
#define KNZ      8
#define DIM      9
#define NTHREADS 512
#define WPB      (NTHREADS / 64)            // 8 waves per block
#define VPW      16                         // vertices per wave-task
#define NTASK    (VNUM / VPW)               // 6250
#define NBLK     ((NTASK + WPB - 1) / WPB)  // 782

typedef float vfloat4 __attribute__((ext_vector_type(4)));  // native vector:
// __builtin_nontemporal_store requires a clang vector type, not HIP's float4.

// out[b, v, d] = sum_k softmax(ws[v*8..v*8+8))[k] * base_fs[b, vb[v*8+k], d]
// One wave = one task of 16 vertices. No cross-lane ops (ds_bpermute) in the
// work path: each lane loads its vertex's 8 (ws, vb) directly from global
// (8-lane redundant, coalesced+L2-broadcast) and does the softmax serially in
// registers. The LDS pipe carries only the fs gathers + the store staging.
__global__ __launch_bounds__(NTHREADS, 4)
void skin_fused(const float* __restrict__ base_fs,
                const float* __restrict__ ws,
                const int*   __restrict__ vb_index,
                float*       __restrict__ out)
{
    // d0..7 of each (b,base) row as one 16B bf16 quad, XOR-swizzled by b so the
    // random-base gather is bank-balanced: quad (b,base) lives at base^(b&7).
    __shared__ __align__(16) unsigned short fs_q[BATCH * BASE_N * 8];  // 16 KB
    // d8 of (b, b+8) paired as float2, slot-swizzled: pair(b0,base) at
    // base*8 + (b0 ^ (base&7))  -> ds_read_b64 serves both batches, exact f32
    __shared__ __align__(8) float fs_d8p[BASE_N * 8 * 2];              //  4 KB
    // per-wave output staging (8 batches x 8 vertices x 9 dims)
    __shared__ __align__(16) float stage[WPB][8 * 72];                 // 18 KB
    // total: 38912 B -> 4 blocks/CU by LDS

    const int t    = threadIdx.x;
    const int wid  = t >> 6;
    const int lane = t & 63;

    const int  task   = blockIdx.x * WPB + wid;
    const bool active = (task < NTASK);
    const int  v0     = task * VPW;

    // ---- Phase 0 (once per block): stage base_fs -> LDS (bf16 + f32 pairs)
    for (int r = t; r < BATCH * BASE_N; r += NTHREADS) {
        const int b = r >> 6, base = r & 63;
        const float* src = base_fs + r * DIM;
        float v[DIM];
        #pragma unroll
        for (int d = 0; d < DIM; ++d) v[d] = src[d];
        const int qi = (b * 64 + (base ^ (b & 7))) * 8;
        #pragma unroll
        for (int d = 0; d < 8; ++d) {
            unsigned int u = __float_as_uint(v[d]);
            u = (u + 0x7fffu + ((u >> 16) & 1u)) >> 16;   // RNE f32->bf16
            fs_q[qi + d] = (unsigned short)u;
        }
        fs_d8p[(base * 8 + ((b & 7) ^ (base & 7))) * 2 + (b >> 3)] = v[8];
    }
    __syncthreads();            // the ONLY barrier
    if (!active) return;

    const int vloc = lane >> 3;     // vertex within 8-v half (0..7)
    const int b0   = lane & 7;      // batch id, low half    (0..7)
    float* const stg = stage[wid];

    #pragma unroll
    for (int h = 0; h < 2; ++h) {
        const int vbase = v0 + h * 8;
        const int vme   = vbase + vloc;          // this lane's vertex

        // Own-vertex (ws, vb): 2x float4 + 2x int4, 32B-aligned, 8-lane
        // redundant -> per wave-instr: 8 distinct 16B segs, fully coalesced.
        const float4 wa = *(const float4*)(ws + (size_t)vme * 8);
        const float4 wb = *(const float4*)(ws + (size_t)vme * 8 + 4);
        const int4   ba = *(const int4*)(vb_index + (size_t)vme * 8);
        const int4   bb = *(const int4*)(vb_index + (size_t)vme * 8 + 4);

        float w[KNZ] = {wa.x, wa.y, wa.z, wa.w, wb.x, wb.y, wb.z, wb.w};
        const int bs[KNZ] = {ba.x, ba.y, ba.z, ba.w, bb.x, bb.y, bb.z, bb.w};

        // serial softmax, all in registers (no cross-lane ops)
        float m = fmaxf(fmaxf(fmaxf(w[0], w[1]), fmaxf(w[2], w[3])),
                        fmaxf(fmaxf(w[4], w[5]), fmaxf(w[6], w[7])));
        float s = 0.f;
        #pragma unroll
        for (int k = 0; k < KNZ; ++k) { w[k] = __expf(w[k] - m); s += w[k]; }
        const float inv = 1.0f / s;
        #pragma unroll
        for (int k = 0; k < KNZ; ++k) w[k] *= inv;

        float acc0[DIM], acc1[DIM];
        #pragma unroll
        for (int d = 0; d < DIM; ++d) { acc0[d] = 0.f; acc1[d] = 0.f; }

        #pragma unroll
        for (int k = 0; k < KNZ; ++k) {
            const float wk = w[k];
            const int   bk = bs[k];
            // swizzled quad: for fixed k the 64 lanes hit each of the 8 b128
            // bank-slots exactly 8 times -> no excess conflict by construction
            const int sx = (bk ^ b0) << 3;                 // ushort units
            const uint4 q0 = *(const uint4*)(fs_q + b0 * 512 + sx);
            const uint4 q1 = *(const uint4*)(fs_q + (b0 + 8) * 512 + sx);
            const float2 dp = *(const float2*)(fs_d8p + (bk * 8 + (b0 ^ (bk & 7))) * 2);
            float f;
            f = __uint_as_float(q0.x << 16);          acc0[0] = fmaf(wk, f, acc0[0]);
            f = __uint_as_float(q0.x & 0xffff0000u);  acc0[1] = fmaf(wk, f, acc0[1]);
            f = __uint_as_float(q0.y << 16);          acc0[2] = fmaf(wk, f, acc0[2]);
            f = __uint_as_float(q0.y & 0xffff0000u);  acc0[3] = fmaf(wk, f, acc0[3]);
            f = __uint_as_float(q0.z << 16);          acc0[4] = fmaf(wk, f, acc0[4]);
            f = __uint_as_float(q0.z & 0xffff0000u);  acc0[5] = fmaf(wk, f, acc0[5]);
            f = __uint_as_float(q0.w << 16);          acc0[6] = fmaf(wk, f, acc0[6]);
            f = __uint_as_float(q0.w & 0xffff0000u);  acc0[7] = fmaf(wk, f, acc0[7]);
            acc0[8] = fmaf(wk, dp.x, acc0[8]);
            f = __uint_as_float(q1.x << 16);          acc1[0] = fmaf(wk, f, acc1[0]);
            f = __uint_as_float(q1.x & 0xffff0000u);  acc1[1] = fmaf(wk, f, acc1[1]);
            f = __uint_as_float(q1.y << 16);          acc1[2] = fmaf(wk, f, acc1[2]);
            f = __uint_as_float(q1.y & 0xffff0000u);  acc1[3] = fmaf(wk, f, acc1[3]);
            f = __uint_as_float(q1.z << 16);          acc1[4] = fmaf(wk, f, acc1[4]);
            f = __uint_as_float(q1.z & 0xffff0000u);  acc1[5] = fmaf(wk, f, acc1[5]);
            f = __uint_as_float(q1.w << 16);          acc1[6] = fmaf(wk, f, acc1[6]);
            f = __uint_as_float(q1.w & 0xffff0000u);  acc1[7] = fmaf(wk, f, acc1[7]);
            acc1[8] = fmaf(wk, dp.y, acc1[8]);
        }

        // Wave-local stage -> fully coalesced, 16B-aligned vfloat4 NT stores.
        // In-wave DS program order makes stage reuse safe without barriers.
        // Per-task out region = 576B = 9 aligned 64B lines, single-wave-owned.
        #pragma unroll
        for (int d = 0; d < DIM; ++d) stg[b0 * 72 + vloc * 9 + d] = acc0[d];
        #pragma unroll
        for (int j = 0; j < 3; ++j) {
            const int i = lane + j * 64;
            if (j < 2 || i < 144) {
                const int b = (int)((unsigned)i / 18u);
                const int f = i - b * 18;
                const vfloat4 val = *(const vfloat4*)(stg + b * 72 + f * 4);
                __builtin_nontemporal_store(
                    val, (vfloat4*)(out + ((size_t)b * VNUM + vbase) * DIM + f * 4));
            }
        }

        #pragma unroll
        for (int d = 0; d < DIM; ++d) stg[b0 * 72 + vloc * 9 + d] = acc1[d];
        #pragma unroll
        for (int j = 0; j < 3; ++j) {
            const int i = lane + j * 64;
            if (j < 2 || i < 144) {
                const int b = (int)((unsigned)i / 18u);
                const int f = i - b * 18;
                const vfloat4 val = *(const vfloat4*)(stg + b * 72 + f * 4);
                __builtin_nontemporal_store(
                    val, (vfloat4*)(out + ((size_t)(b + 8) * VNUM + vbase) * DIM + f * 4));
            }
        }
    }
}

extern "C" void kernel_launch(void* const* d_in, const int* in_sizes, int n_in,
                              void* d_out, int out_size, void* d_ws, size_t ws_size,
                              hipStream_t stream) {
    const float* base_fs  = (const float*)d_in[0];   // [16, 576]
    const float* ws       = (const float*)d_in[1];   // [800000]
    const int*   vb_index = (const int*)d_in[2];     // [800000]
    // d_in[3] = vv_index: structurally repeat(arange(V),8) — not needed.
    float* out = (float*)d_out;                      // [16, 100000, 9]

    dim3 grid(NBLK), block(NTHREADS);
    hipLaunchKernelGGL(skin_fused, grid, block, 0, stream,
                       base_fs, ws, vb_index, out);
}

// Round 5
// 95.501 us; speedup vs baseline: 1.0132x; 1.0132x over previous
//
#include <hip/hip_runtime.h>

#define BATCH    16
#define BASE_N   64
#define VNUM     100000
#define KNZ      8
#define DIM      9
#define NTHREADS 512
#define WPB      (NTHREADS / 64)            // 8 waves per block
#define VPW      16                         // vertices per wave-task
#define NTASK    (VNUM / VPW)               // 6250
#define GRID     1024                       // 4 blocks/CU exactly, all resident

typedef float vfloat4 __attribute__((ext_vector_type(4)));  // native vector:
// __builtin_nontemporal_store requires a clang vector type, not HIP's float4.

// out[b, v, d] = sum_k softmax(ws[v*8..v*8+8))[k] * base_fs[b, vb[v*8+k], d]
// One wave = one task of 16 vertices; no cross-lane ops in the work path.
// Task map: task = bid + 1024*wid  (bijective onto 0..8191, active < 6250).
// -> blocks 0-105 have 7 active waves, 106-1023 have 6; with 4 blocks/CU
// round-robin placement every CU gets 24-25 active waves (avg 24.4), killing
// the 31% tail of the old 782-block grid (14 CUs carried a 4th full block).
__global__ __launch_bounds__(NTHREADS, 4)
void skin_fused(const float* __restrict__ base_fs,
                const float* __restrict__ ws,
                const int*   __restrict__ vb_index,
                float*       __restrict__ out)
{
    // d0..7 of each (b,base) row as one 16B bf16 quad, XOR-swizzled by b so the
    // random-base gather is bank-balanced: quad (b,base) lives at base^(b&7).
    __shared__ __align__(16) unsigned short fs_q[BATCH * BASE_N * 8];  // 16 KB
    // d8 of (b, b+8) paired as float2, slot-swizzled: pair(b0,base) at
    // base*8 + (b0 ^ (base&7))  -> ds_read_b64 serves both batches, exact f32
    __shared__ __align__(8) float fs_d8p[BASE_N * 8 * 2];              //  4 KB
    // per-wave output staging (8 batches x 8 vertices x 9 dims)
    __shared__ __align__(16) float stage[WPB][8 * 72];                 // 18 KB
    // total: 38912 B -> 4 blocks/CU by LDS

    const int t    = threadIdx.x;
    const int wid  = t >> 6;
    const int lane = t & 63;

    const int  task   = blockIdx.x + GRID * wid;   // balanced wave->task map
    const bool active = (task < NTASK);
    const int  v0     = task * VPW;

    // ---- Phase 0 (once per block): stage base_fs -> LDS (bf16 + f32 pairs)
    for (int r = t; r < BATCH * BASE_N; r += NTHREADS) {
        const int b = r >> 6, base = r & 63;
        const float* src = base_fs + r * DIM;
        float v[DIM];
        #pragma unroll
        for (int d = 0; d < DIM; ++d) v[d] = src[d];
        const int qi = (b * 64 + (base ^ (b & 7))) * 8;
        #pragma unroll
        for (int d = 0; d < 8; ++d) {
            unsigned int u = __float_as_uint(v[d]);
            u = (u + 0x7fffu + ((u >> 16) & 1u)) >> 16;   // RNE f32->bf16
            fs_q[qi + d] = (unsigned short)u;
        }
        fs_d8p[(base * 8 + ((b & 7) ^ (base & 7))) * 2 + (b >> 3)] = v[8];
    }
    __syncthreads();            // the ONLY barrier
    if (!active) return;

    const int vloc = lane >> 3;     // vertex within 8-v half (0..7)
    const int b0   = lane & 7;      // batch id, low half    (0..7)
    float* const stg = stage[wid];

    #pragma unroll
    for (int h = 0; h < 2; ++h) {
        const int vbase = v0 + h * 8;
        const int vme   = vbase + vloc;          // this lane's vertex

        // Own-vertex (ws, vb): 2x float4 + 2x int4, 32B-aligned, 8-lane
        // redundant -> per wave-instr: 8 distinct 16B segs, fully coalesced.
        const float4 wa = *(const float4*)(ws + (size_t)vme * 8);
        const float4 wb = *(const float4*)(ws + (size_t)vme * 8 + 4);
        const int4   ba = *(const int4*)(vb_index + (size_t)vme * 8);
        const int4   bb = *(const int4*)(vb_index + (size_t)vme * 8 + 4);

        float w[KNZ] = {wa.x, wa.y, wa.z, wa.w, wb.x, wb.y, wb.z, wb.w};
        const int bs[KNZ] = {ba.x, ba.y, ba.z, ba.w, bb.x, bb.y, bb.z, bb.w};

        // serial softmax, all in registers (no cross-lane ops)
        float m = fmaxf(fmaxf(fmaxf(w[0], w[1]), fmaxf(w[2], w[3])),
                        fmaxf(fmaxf(w[4], w[5]), fmaxf(w[6], w[7])));
        float s = 0.f;
        #pragma unroll
        for (int k = 0; k < KNZ; ++k) { w[k] = __expf(w[k] - m); s += w[k]; }
        const float inv = 1.0f / s;
        #pragma unroll
        for (int k = 0; k < KNZ; ++k) w[k] *= inv;

        float acc0[DIM], acc1[DIM];
        #pragma unroll
        for (int d = 0; d < DIM; ++d) { acc0[d] = 0.f; acc1[d] = 0.f; }

        #pragma unroll
        for (int k = 0; k < KNZ; ++k) {
            const float wk = w[k];
            const int   bk = bs[k];
            // swizzled quad: for fixed k the 64 lanes hit each of the 8 b128
            // bank-slots exactly 8 times -> no excess conflict by construction
            const int sx = (bk ^ b0) << 3;                 // ushort units
            const uint4 q0 = *(const uint4*)(fs_q + b0 * 512 + sx);
            const uint4 q1 = *(const uint4*)(fs_q + (b0 + 8) * 512 + sx);
            const float2 dp = *(const float2*)(fs_d8p + (bk * 8 + (b0 ^ (bk & 7))) * 2);
            float f;
            f = __uint_as_float(q0.x << 16);          acc0[0] = fmaf(wk, f, acc0[0]);
            f = __uint_as_float(q0.x & 0xffff0000u);  acc0[1] = fmaf(wk, f, acc0[1]);
            f = __uint_as_float(q0.y << 16);          acc0[2] = fmaf(wk, f, acc0[2]);
            f = __uint_as_float(q0.y & 0xffff0000u);  acc0[3] = fmaf(wk, f, acc0[3]);
            f = __uint_as_float(q0.z << 16);          acc0[4] = fmaf(wk, f, acc0[4]);
            f = __uint_as_float(q0.z & 0xffff0000u);  acc0[5] = fmaf(wk, f, acc0[5]);
            f = __uint_as_float(q0.w << 16);          acc0[6] = fmaf(wk, f, acc0[6]);
            f = __uint_as_float(q0.w & 0xffff0000u);  acc0[7] = fmaf(wk, f, acc0[7]);
            acc0[8] = fmaf(wk, dp.x, acc0[8]);
            f = __uint_as_float(q1.x << 16);          acc1[0] = fmaf(wk, f, acc1[0]);
            f = __uint_as_float(q1.x & 0xffff0000u);  acc1[1] = fmaf(wk, f, acc1[1]);
            f = __uint_as_float(q1.y << 16);          acc1[2] = fmaf(wk, f, acc1[2]);
            f = __uint_as_float(q1.y & 0xffff0000u);  acc1[3] = fmaf(wk, f, acc1[3]);
            f = __uint_as_float(q1.z << 16);          acc1[4] = fmaf(wk, f, acc1[4]);
            f = __uint_as_float(q1.z & 0xffff0000u);  acc1[5] = fmaf(wk, f, acc1[5]);
            f = __uint_as_float(q1.w << 16);          acc1[6] = fmaf(wk, f, acc1[6]);
            f = __uint_as_float(q1.w & 0xffff0000u);  acc1[7] = fmaf(wk, f, acc1[7]);
            acc1[8] = fmaf(wk, dp.y, acc1[8]);
        }

        // Wave-local stage -> fully coalesced, 16B-aligned vfloat4 NT stores.
        // In-wave DS program order makes stage reuse safe without barriers.
        // Per-task out region = 576B = 9 aligned 64B lines, single-wave-owned.
        #pragma unroll
        for (int d = 0; d < DIM; ++d) stg[b0 * 72 + vloc * 9 + d] = acc0[d];
        #pragma unroll
        for (int j = 0; j < 3; ++j) {
            const int i = lane + j * 64;
            if (j < 2 || i < 144) {
                const int b = (int)((unsigned)i / 18u);
                const int f = i - b * 18;
                const vfloat4 val = *(const vfloat4*)(stg + b * 72 + f * 4);
                __builtin_nontemporal_store(
                    val, (vfloat4*)(out + ((size_t)b * VNUM + vbase) * DIM + f * 4));
            }
        }

        #pragma unroll
        for (int d = 0; d < DIM; ++d) stg[b0 * 72 + vloc * 9 + d] = acc1[d];
        #pragma unroll
        for (int j = 0; j < 3; ++j) {
            const int i = lane + j * 64;
            if (j < 2 || i < 144) {
                const int b = (int)((unsigned)i / 18u);
                const int f = i - b * 18;
                const vfloat4 val = *(const vfloat4*)(stg + b * 72 + f * 4);
                __builtin_nontemporal_store(
                    val, (vfloat4*)(out + ((size_t)(b + 8) * VNUM + vbase) * DIM + f * 4));
            }
        }
    }
}

extern "C" void kernel_launch(void* const* d_in, const int* in_sizes, int n_in,
                              void* d_out, int out_size, void* d_ws, size_t ws_size,
                              hipStream_t stream) {
    const float* base_fs  = (const float*)d_in[0];   // [16, 576]
    const float* ws       = (const float*)d_in[1];   // [800000]
    const int*   vb_index = (const int*)d_in[2];     // [800000]
    // d_in[3] = vv_index: structurally repeat(arange(V),8) — not needed.
    float* out = (float*)d_out;                      // [16, 100000, 9]

    dim3 grid(GRID), block(NTHREADS);
    hipLaunchKernelGGL(skin_fused, grid, block, 0, stream,
                       base_fs, ws, vb_index, out);
}